// Round 13
// baseline (430.285 us; speedup 1.0000x reference)
//
#include <hip/hip_runtime.h>
#include <hip/hip_cooperative_groups.h>

namespace cg = cooperative_groups;

#define TT 4096
#define KS 8

// ws float offsets (total 1,671,168 floats = 6.7 MB)
#define OFF_GPART 0        // [2][256][64] transposed partials
#define OFF_QH    32768    // bf16 [2][4096][16]
#define OFF_QL    98304
#define OFF_KH    163840
#define OFF_KL    229376
#define OFF_VT    294912   // bf16 [2][16][4096] (V transposed)
#define OFF_Y     360448   // [48][4096]
#define OFF_P     557056   // [2][KS][17][4096] flash partials (l, acc0..15), fixed-shift
#define OFF_C1    557056   // alias (conv stage runs after attn complete) (5,12,1023)
#define OFF_C2    618496   // (5,6,255)

typedef __attribute__((ext_vector_type(8))) short short8;
typedef __attribute__((ext_vector_type(4))) float f32x4;

__device__ __forceinline__ float relu6f(float v){ return fminf(fmaxf(v, 0.f), 6.f); }
__device__ __forceinline__ unsigned short f2bf(float f){   // RNE float->bf16 bits
  unsigned int u = __float_as_uint(f);
  return (unsigned short)((u + 0x7FFFu + ((u>>16)&1u)) >> 16);
}
__device__ __forceinline__ float bf2f(unsigned short s){
  return __uint_as_float(((unsigned int)s)<<16);
}

// ================= phase bodies (shared by mega + standalone) =================

__device__ __forceinline__ void phase_gpart(int b, int tid,
    const float* __restrict__ x, float* __restrict__ ws){
  const int i = tid >> 4, j = tid & 15;
  const int t0 = b*64;
  const float4* ei4 = reinterpret_cast<const float4*>(x + (size_t)(1+i)*TT + t0);
  const float4* ej4 = reinterpret_cast<const float4*>(x + (size_t)(1+j)*TT + t0);
  const float4* wA4 = reinterpret_cast<const float4*>(x + t0);
  const float4* wB4 = reinterpret_cast<const float4*>(x + (size_t)17*TT + t0);
  float gA = 0.f, gB = 0.f;
  #pragma unroll 4
  for (int u = 0; u < 16; ++u){
    float4 a = ei4[u], c = ej4[u], wa = wA4[u], wb = wB4[u];
    float p0 = a.x*c.x, p1 = a.y*c.y, p2 = a.z*c.z, p3 = a.w*c.w;
    gA = fmaf(wa.x, p0, gA); gA = fmaf(wa.y, p1, gA); gA = fmaf(wa.z, p2, gA); gA = fmaf(wa.w, p3, gA);
    gB = fmaf(wb.x, p0, gB); gB = fmaf(wb.y, p1, gB); gB = fmaf(wb.z, p2, gB); gB = fmaf(wb.w, p3, gB);
  }
  ws[OFF_GPART + (size_t)tid*64 + b]       = gA;   // cm=0
  ws[OFF_GPART + (size_t)(256+tid)*64 + b] = gB;   // cm=1
}

// b < 32, 256 threads; smem >= 1072 floats
__device__ __forceinline__ void phase_qkv(int b, int tid,
    const float* __restrict__ x,
    const float* __restrict__ cm1W, const float* __restrict__ cm1b,
    const float* __restrict__ cm2W, const float* __restrict__ cm2b,
    float* __restrict__ ws, float* smem){
  float* sG  = smem;         // 256
  float* sWf = smem + 256;   // 768
  float* sB  = smem + 1024;  // 48
  const int cm = b >> 4;
  {
    const float4* g4 = reinterpret_cast<const float4*>(ws + OFF_GPART + (size_t)(cm*256 + tid)*64);
    float g0 = 0.f;
    #pragma unroll
    for (int u = 0; u < 16; ++u){
      float4 a = g4[u];
      g0 += (a.x + a.y) + (a.z + a.w);
    }
    sG[tid] = g0;
  }
  const float* W  = cm ? cm2W : cm1W;
  const float* Bb = cm ? cm2b : cm1b;
  sWf[tid]       = W[tid];
  sWf[tid + 256] = W[tid + 256];
  sWf[tid + 512] = W[tid + 512];
  if (tid < 48) sB[tid] = Bb[tid];
  __syncthreads();

  const float4* sG4  = reinterpret_cast<const float4*>(sG);
  const float4* sW04 = reinterpret_cast<const float4*>(sWf);
  const float4* sW14 = reinterpret_cast<const float4*>(sWf + 256);
  const float4* sW24 = reinterpret_cast<const float4*>(sWf + 512);

  const int t = (b & 15)*256 + tid;
  float e[16], p[16], w2[16];
  const float wav = x[(size_t)(cm ? 17 : 0)*TT + t];
  #pragma unroll
  for (int d = 0; d < 16; ++d){ e[d] = x[(size_t)(1+d)*TT + t]; p[d] = wav * e[d]; }

  #pragma unroll
  for (int c = 0; c < 16; ++c){
    float a = 0.f;
    #pragma unroll
    for (int dv = 0; dv < 4; ++dv){
      float4 gv = sG4[c*4+dv];
      a = fmaf(gv.x, p[4*dv+0], a); a = fmaf(gv.y, p[4*dv+1], a);
      a = fmaf(gv.z, p[4*dv+2], a); a = fmaf(gv.w, p[4*dv+3], a);
    }
    w2[c] = a;
  }
  float q[16], kk[16], vv[16];
  #pragma unroll
  for (int c = 0; c < 16; ++c){
    float aq = sB[c], ak = sB[16+c], av = sB[32+c];
    #pragma unroll
    for (int dv = 0; dv < 4; ++dv){
      float4 w0 = sW04[c*4+dv], w1 = sW14[c*4+dv], w3 = sW24[c*4+dv];
      aq = fmaf(w0.x, e[4*dv+0], aq);  aq = fmaf(w0.y, e[4*dv+1], aq);
      aq = fmaf(w0.z, e[4*dv+2], aq);  aq = fmaf(w0.w, e[4*dv+3], aq);
      ak = fmaf(w1.x, w2[4*dv+0], ak); ak = fmaf(w1.y, w2[4*dv+1], ak);
      ak = fmaf(w1.z, w2[4*dv+2], ak); ak = fmaf(w1.w, w2[4*dv+3], ak);
      av = fmaf(w3.x, w2[4*dv+0], av); av = fmaf(w3.y, w2[4*dv+1], av);
      av = fmaf(w3.z, w2[4*dv+2], av); av = fmaf(w3.w, w2[4*dv+3], av);
    }
    q[c] = relu6f(aq); kk[c] = relu6f(ak); vv[c] = relu6f(av);
  }
  unsigned short qhv[16], qlv[16], khv[16], klv[16];
  #pragma unroll
  for (int d = 0; d < 16; ++d){
    qhv[d] = f2bf(q[d]);  qlv[d] = f2bf(q[d]  - bf2f(qhv[d]));
    khv[d] = f2bf(kk[d]); klv[d] = f2bf(kk[d] - bf2f(khv[d]));
  }
  const size_t rowus = ((size_t)cm*TT + t)*16;
  unsigned int wq[8];
  #pragma unroll
  for (int xx = 0; xx < 8; ++xx) wq[xx] = (unsigned int)qhv[2*xx] | ((unsigned int)qhv[2*xx+1]<<16);
  ((uint4*)((unsigned short*)(ws+OFF_QH)+rowus))[0] = make_uint4(wq[0],wq[1],wq[2],wq[3]);
  ((uint4*)((unsigned short*)(ws+OFF_QH)+rowus))[1] = make_uint4(wq[4],wq[5],wq[6],wq[7]);
  #pragma unroll
  for (int xx = 0; xx < 8; ++xx) wq[xx] = (unsigned int)qlv[2*xx] | ((unsigned int)qlv[2*xx+1]<<16);
  ((uint4*)((unsigned short*)(ws+OFF_QL)+rowus))[0] = make_uint4(wq[0],wq[1],wq[2],wq[3]);
  ((uint4*)((unsigned short*)(ws+OFF_QL)+rowus))[1] = make_uint4(wq[4],wq[5],wq[6],wq[7]);
  #pragma unroll
  for (int xx = 0; xx < 8; ++xx) wq[xx] = (unsigned int)khv[2*xx] | ((unsigned int)khv[2*xx+1]<<16);
  ((uint4*)((unsigned short*)(ws+OFF_KH)+rowus))[0] = make_uint4(wq[0],wq[1],wq[2],wq[3]);
  ((uint4*)((unsigned short*)(ws+OFF_KH)+rowus))[1] = make_uint4(wq[4],wq[5],wq[6],wq[7]);
  #pragma unroll
  for (int xx = 0; xx < 8; ++xx) wq[xx] = (unsigned int)klv[2*xx] | ((unsigned int)klv[2*xx+1]<<16);
  ((uint4*)((unsigned short*)(ws+OFF_KL)+rowus))[0] = make_uint4(wq[0],wq[1],wq[2],wq[3]);
  ((uint4*)((unsigned short*)(ws+OFF_KL)+rowus))[1] = make_uint4(wq[4],wq[5],wq[6],wq[7]);
  unsigned short* vtp = (unsigned short*)(ws+OFF_VT) + (size_t)cm*16*TT;
  #pragma unroll
  for (int d = 0; d < 16; ++d) vtp[(size_t)d*TT + t] = f2bf(vv[d]);

  if (cm == 0){
    #pragma unroll
    for (int d = 0; d < 16; ++d) ws[OFF_Y + (size_t)(16+d)*TT + t] = e[d];
  }
}

// unit < 2048
__device__ __forceinline__ void phase_attn(int unit, int lane, float* __restrict__ ws){
  const int cm = unit >> 10;
  const int rem = unit & 1023;
  const int qt2 = rem >> 3;         // 128 q-pair tiles (32 queries)
  const int ks = rem & 7;           // 8 key slices of 512
  const int i = lane & 15, g = lane >> 4;
  const int gb = (g & 1) * 8;

  const unsigned short* qh = (const unsigned short*)(ws + OFF_QH) + (size_t)cm*TT*16;
  const unsigned short* ql = (const unsigned short*)(ws + OFF_QL) + (size_t)cm*TT*16;
  const unsigned short* kh = (const unsigned short*)(ws + OFF_KH) + (size_t)cm*TT*16;
  const unsigned short* kl = (const unsigned short*)(ws + OFF_KL) + (size_t)cm*TT*16;
  const unsigned short* vt = (const unsigned short*)(ws + OFF_VT) + (size_t)cm*16*TT;
  const unsigned short* kbase = (g < 2) ? kh : kl;   // A rows: [Kh | Kl] along K-dim

  const int qA = qt2*32 + i, qB = qA + 16;
  const short8 b1A = *(const short8*)(qh + (size_t)qA*16 + gb);
  const short8 b2A = *(const short8*)(ql + (size_t)qA*16 + gb);
  const short8 b1B = *(const short8*)(qh + (size_t)qB*16 + gb);
  const short8 b2B = *(const short8*)(ql + (size_t)qB*16 + gb);

  const int key0 = ks*512;
  const int keyA = ((i>>2)<<3) + (i&3);    // interleave permute pi(i)
  f32x4 accA = {0.f,0.f,0.f,0.f}, accB = {0.f,0.f,0.f,0.f};
  float lsumA = 0.f, lsumB = 0.f;

  for (int t = 0; t < 16; ++t){
    const int k0 = key0 + t*32;
    const short8 a0 = *(const short8*)(kbase + ((size_t)(k0 + keyA))*16 + gb);
    const short8 a1 = *(const short8*)(kbase + ((size_t)(k0 + keyA + 4))*16 + gb);
    f32x4 d0A = {0.f,0.f,0.f,0.f}, d1A = {0.f,0.f,0.f,0.f};
    f32x4 d0B = {0.f,0.f,0.f,0.f}, d1B = {0.f,0.f,0.f,0.f};
    d0A = __builtin_amdgcn_mfma_f32_16x16x32_bf16(a0, b1A, d0A, 0,0,0);
    d0A = __builtin_amdgcn_mfma_f32_16x16x32_bf16(a0, b2A, d0A, 0,0,0);
    d1A = __builtin_amdgcn_mfma_f32_16x16x32_bf16(a1, b1A, d1A, 0,0,0);
    d1A = __builtin_amdgcn_mfma_f32_16x16x32_bf16(a1, b2A, d1A, 0,0,0);
    d0B = __builtin_amdgcn_mfma_f32_16x16x32_bf16(a0, b1B, d0B, 0,0,0);
    d0B = __builtin_amdgcn_mfma_f32_16x16x32_bf16(a0, b2B, d0B, 0,0,0);
    d1B = __builtin_amdgcn_mfma_f32_16x16x32_bf16(a1, b1B, d1B, 0,0,0);
    d1B = __builtin_amdgcn_mfma_f32_16x16x32_bf16(a1, b2B, d1B, 0,0,0);
    float p0A[4], p1A[4], p0B[4], p1B[4];
    #pragma unroll
    for (int r = 0; r < 4; ++r){
      p0A[r] = __expf(fminf(d0A[r],100.f) - 32.f); lsumA += p0A[r];
      p1A[r] = __expf(fminf(d1A[r],100.f) - 32.f); lsumA += p1A[r];
      p0B[r] = __expf(fminf(d0B[r],100.f) - 32.f); lsumB += p0B[r];
      p1B[r] = __expf(fminf(d1B[r],100.f) - 32.f); lsumB += p1B[r];
    }
    short8 paA, paB;
    #pragma unroll
    for (int r = 0; r < 4; ++r){
      paA[r]   = (short)f2bf(p0A[r]);
      paA[r+4] = (short)f2bf(p1A[r]);
      paB[r]   = (short)f2bf(p0B[r]);
      paB[r+4] = (short)f2bf(p1B[r]);
    }
    const short8 bv = *(const short8*)(vt + (size_t)i*TT + k0 + g*8);
    accA = __builtin_amdgcn_mfma_f32_16x16x32_bf16(paA, bv, accA, 0,0,0);
    accB = __builtin_amdgcn_mfma_f32_16x16x32_bf16(paB, bv, accB, 0,0,0);
  }
  lsumA += __shfl_xor(lsumA, 16);  lsumA += __shfl_xor(lsumA, 32);
  lsumB += __shfl_xor(lsumB, 16);  lsumB += __shfl_xor(lsumB, 32);
  float* Pb = ws + OFF_P + (size_t)((cm*KS + ks)*17)*TT;
  if (lane < 16){
    Pb[qt2*32 + lane]      = lsumA;
    Pb[qt2*32 + 16 + lane] = lsumB;
  }
  #pragma unroll
  for (int r = 0; r < 4; ++r){
    Pb[(size_t)(1 + i)*TT + qt2*32 + g*4 + r]      = accA[r];
    Pb[(size_t)(1 + i)*TT + qt2*32 + 16 + g*4 + r] = accB[r];
  }
}

__device__ __forceinline__ void phase_sum(int idx, float* __restrict__ ws){
  const int cm = idx / (17*TT);
  const int r  = idx - cm*17*TT;
  const float* Pb = ws + OFF_P + (size_t)cm*KS*17*TT + r;
  float s = 0.f;
  #pragma unroll
  for (int k = 0; k < KS; ++k) s += Pb[(size_t)k*17*TT];
  ws[OFF_P + (size_t)cm*KS*17*TT + r] = s;
}

// gid < 8192
__device__ __forceinline__ void phase_epi(int gid,
    const float* __restrict__ cm1W, const float* __restrict__ cm1b,
    const float* __restrict__ cm2W, const float* __restrict__ cm2b,
    float* __restrict__ ws){
  const int cm = gid >> 12;
  const int q = gid & 4095;
  const float* Mb = ws + OFF_P + (size_t)cm*KS*17*TT + q;
  const float lt = Mb[0];
  float a[16];
  #pragma unroll
  for (int d = 0; d < 16; ++d) a[d] = Mb[(size_t)(1+d)*TT];
  const float invl = 1.f/lt;
  float mx = -1e30f;
  #pragma unroll
  for (int d = 0; d < 16; ++d){ a[d] *= invl; mx = fmaxf(mx, a[d]); }
  float es = 0.f;
  #pragma unroll
  for (int d = 0; d < 16; ++d){ a[d] = __expf(a[d]-mx); es += a[d]; }
  const float invs = 1.f/es;
  const float* W  = cm ? cm2W : cm1W;
  const float* Bb = cm ? cm2b : cm1b;
  #pragma unroll
  for (int c = 0; c < 16; ++c){
    float o = 0.f;
    #pragma unroll
    for (int d = 0; d < 16; ++d) o = fmaf(W[768 + c*16 + d], a[d], o);
    o = relu6f(fmaf(o, invs, Bb[48 + c]));
    ws[OFF_Y + (size_t)((cm ? 32 : 0) + c)*TT + q] = o;
  }
}

// idx < 61380
__device__ __forceinline__ void phase_conv01(int idx,
    const float* __restrict__ cw0, const float* __restrict__ cw1,
    const float* __restrict__ cb, float* __restrict__ ws){
  const int WO = 1023, HO = 12;
  const int ow = idx % WO; int tmp = idx / WO;
  const int oh = tmp % HO; const int oc = tmp / HO;
  const float* y = ws + OFF_Y;
  float yp[4][7];
  #pragma unroll
  for (int r = 0; r < 4; ++r){
    const float* yr = y + (size_t)(4*oh + r)*TT + 4*ow;
    #pragma unroll
    for (int cx = 0; cx < 7; ++cx) yp[r][cx] = yr[cx];
  }
  float a = cb[5 + oc];
  #pragma unroll
  for (int ic = 0; ic < 5; ++ic){
    const float* w0 = cw0 + ic*6;
    const float* w1 = cw1 + ((oc*5+ic)*2)*4;
    #pragma unroll
    for (int kh = 0; kh < 2; ++kh){
      #pragma unroll
      for (int kw = 0; kw < 4; ++kw){
        float c0 = cb[ic];
        c0 = fmaf(w0[0], yp[2*kh][kw],   c0);
        c0 = fmaf(w0[1], yp[2*kh][kw+1], c0);
        c0 = fmaf(w0[2], yp[2*kh][kw+2], c0);
        c0 = fmaf(w0[3], yp[2*kh+1][kw],   c0);
        c0 = fmaf(w0[4], yp[2*kh+1][kw+1], c0);
        c0 = fmaf(w0[5], yp[2*kh+1][kw+2], c0);
        c0 = relu6f(c0);
        a = fmaf(w1[kh*4+kw], c0, a);
      }
    }
  }
  ws[OFF_C1 + idx] = relu6f(a);
}

// idx < 7650
__device__ __forceinline__ void phase_conv2(int idx,
    const float* __restrict__ cw2, const float* __restrict__ cb, float* __restrict__ ws){
  const int ow = idx % 255; int tmp = idx/255;
  const int oh = tmp % 6; const int oc = tmp/6;
  const float* c1 = ws + OFF_C1;
  float a = cb[10 + oc];
  #pragma unroll
  for (int ic = 0; ic < 5; ++ic)
    #pragma unroll
    for (int kh = 0; kh < 2; ++kh)
      #pragma unroll
      for (int kw = 0; kw < 4; ++kw)
        a = fmaf(cw2[((oc*5+ic)*2+kh)*4+kw], c1[(size_t)(ic*12 + 2*oh+kh)*1023 + 4*ow+kw], a);
  ws[OFF_C2 + idx] = relu6f(a);
}

// single block, 256 threads; c2buf 7650, c3buf 1260, hsm 630 floats
__device__ __forceinline__ void phase_tail(int tid,
    float* c2, float* c3, float* hsm,
    const float* __restrict__ cw3, const float* __restrict__ cb,
    const float* __restrict__ fc1W, const float* __restrict__ fc1b,
    const float* __restrict__ fc2W, const float* __restrict__ fc2b,
    const float* __restrict__ ws, float* __restrict__ out){
  for (int i = tid; i < 5*6*255; i += 256) c2[i] = ws[OFF_C2 + i];
  __syncthreads();
  for (int idx = tid; idx < 5*3*84; idx += 256){
    const int ow = idx % 84; int tmp = idx/84;
    const int oh = tmp % 3; const int oc = tmp/3;
    float a = cb[15 + oc];
    #pragma unroll
    for (int ic = 0; ic < 5; ++ic)
      #pragma unroll
      for (int kh = 0; kh < 2; ++kh)
        #pragma unroll
        for (int kw = 0; kw < 4; ++kw)
          a = fmaf(cw3[((oc*5+ic)*2+kh)*4+kw], c2[(ic*6 + 2*oh+kh)*255 + 3*ow+kw], a);
    c3[idx] = relu6f(a);
  }
  __syncthreads();
  for (int i = tid; i < 630; i += 256){
    const int s = i / 15, kx = i % 15;
    const float* row = c3 + s*30;
    float a = fc1b[kx];
    #pragma unroll
    for (int n = 0; n < 30; ++n) a = fmaf(fc1W[kx*30+n], row[n], a);
    hsm[i] = 1.f/(1.f + __expf(-a));
  }
  __syncthreads();
  if (tid < 42){
    const float* h = hsm + tid*15;
    float l0 = fc2b[0], l1 = fc2b[1];
    #pragma unroll
    for (int kx = 0; kx < 15; ++kx){
      l0 = fmaf(fc2W[kx],    h[kx], l0);
      l1 = fmaf(fc2W[15+kx], h[kx], l1);
    }
    float mx = fmaxf(l0, l1);
    float e0 = __expf(l0-mx), e1 = __expf(l1-mx);
    float s = e0 + e1;
    out[tid*2]   = e0/s;
    out[tid*2+1] = e1/s;
  }
}

// ================= cooperative mega-kernel =================
__global__ __launch_bounds__(256) void k_mega(
    const float* __restrict__ x,
    const float* __restrict__ cm1W, const float* __restrict__ cm1b,
    const float* __restrict__ cm2W, const float* __restrict__ cm2b,
    const float* __restrict__ cw0,  const float* __restrict__ cw1,
    const float* __restrict__ cw2,  const float* __restrict__ cw3,
    const float* __restrict__ cb,
    const float* __restrict__ fc1W, const float* __restrict__ fc1b,
    const float* __restrict__ fc2W, const float* __restrict__ fc2b,
    float* __restrict__ ws, float* __restrict__ out){
  __shared__ float smem[9540];   // 38.2 KB: max(qkv 1072, tail 9540)
  cg::grid_group grid = cg::this_grid();
  const int b = blockIdx.x, tid = threadIdx.x;

  if (b < 64) phase_gpart(b, tid, x, ws);
  grid.sync();
  if (b < 32) phase_qkv(b, tid, x, cm1W, cm1b, cm2W, cm2b, ws, smem);
  grid.sync();
  phase_attn(b*4 + (tid>>6), tid & 63, ws);
  grid.sync();
  {
    int idx = b*256 + tid;
    phase_sum(idx, ws);                       // 131072 < 139264 always valid
    int idx2 = idx + 131072;
    if (idx2 < 2*17*TT) phase_sum(idx2, ws);
  }
  grid.sync();
  if (b < 32) phase_epi(b*256 + tid, cm1W, cm1b, cm2W, cm2b, ws);
  grid.sync();
  { int idx = b*256 + tid; if (idx < 61380) phase_conv01(idx, cw0, cw1, cb, ws); }
  grid.sync();
  { int idx = b*256 + tid; if (idx < 7650) phase_conv2(idx, cw2, cb, ws); }
  grid.sync();
  if (b == 0) phase_tail(tid, smem, smem + 7650, smem + 8910,
                         cw3, cb, fc1W, fc1b, fc2W, fc2b, ws, out);
}

// ================= standalone fallback kernels =================
__global__ __launch_bounds__(256) void k_gpart(const float* __restrict__ x, float* __restrict__ ws){
  phase_gpart(blockIdx.x, threadIdx.x, x, ws);
}
__global__ __launch_bounds__(256) void k_qkv(const float* __restrict__ x,
    const float* __restrict__ cm1W, const float* __restrict__ cm1b,
    const float* __restrict__ cm2W, const float* __restrict__ cm2b,
    float* __restrict__ ws){
  __shared__ float smem[1072];
  phase_qkv(blockIdx.x, threadIdx.x, x, cm1W, cm1b, cm2W, cm2b, ws, smem);
}
__global__ __launch_bounds__(256) void k_attn_main(float* __restrict__ ws){
  phase_attn(blockIdx.x*4 + (threadIdx.x>>6), threadIdx.x & 63, ws);
}
__global__ __launch_bounds__(256) void k_attn_sum(float* __restrict__ ws){
  const int idx = blockIdx.x*256 + threadIdx.x;
  if (idx < 2*17*TT) phase_sum(idx, ws);
}
__global__ __launch_bounds__(256) void k_attn_epi(
    const float* __restrict__ cm1W, const float* __restrict__ cm1b,
    const float* __restrict__ cm2W, const float* __restrict__ cm2b,
    float* __restrict__ ws){
  phase_epi(blockIdx.x*256 + threadIdx.x, cm1W, cm1b, cm2W, cm2b, ws);
}
__global__ __launch_bounds__(256) void k_conv01(const float* __restrict__ cw0,
    const float* __restrict__ cw1, const float* __restrict__ cb, float* __restrict__ ws){
  const int idx = blockIdx.x*256 + threadIdx.x;
  if (idx < 61380) phase_conv01(idx, cw0, cw1, cb, ws);
}
__global__ __launch_bounds__(256) void k_conv2(const float* __restrict__ cw2,
    const float* __restrict__ cb, float* __restrict__ ws){
  const int idx = blockIdx.x*256 + threadIdx.x;
  if (idx < 7650) phase_conv2(idx, cw2, cb, ws);
}
__global__ __launch_bounds__(256) void k_tail(
    const float* __restrict__ cw3, const float* __restrict__ cb,
    const float* __restrict__ fc1W, const float* __restrict__ fc1b,
    const float* __restrict__ fc2W, const float* __restrict__ fc2b,
    const float* __restrict__ ws, float* __restrict__ out){
  __shared__ float smem[9540];
  phase_tail(threadIdx.x, smem, smem + 7650, smem + 8910,
             cw3, cb, fc1W, fc1b, fc2W, fc2b, ws, out);
}

extern "C" void kernel_launch(void* const* d_in, const int* in_sizes, int n_in,
                              void* d_out, int out_size, void* d_ws, size_t ws_size,
                              hipStream_t stream){
  const float* x    = (const float*)d_in[0];
  const float* cm1W = (const float*)d_in[1];
  const float* cm1b = (const float*)d_in[2];
  const float* cm2W = (const float*)d_in[3];
  const float* cm2b = (const float*)d_in[4];
  const float* cw0  = (const float*)d_in[5];
  const float* cw1  = (const float*)d_in[6];
  const float* cw2  = (const float*)d_in[7];
  const float* cw3  = (const float*)d_in[8];
  const float* cb   = (const float*)d_in[9];
  const float* fc1W = (const float*)d_in[10];
  const float* fc1b = (const float*)d_in[11];
  const float* fc2W = (const float*)d_in[12];
  const float* fc2b = (const float*)d_in[13];
  float* ws  = (float*)d_ws;
  float* out = (float*)d_out;

  void* args[16] = {(void*)&x, (void*)&cm1W, (void*)&cm1b, (void*)&cm2W, (void*)&cm2b,
                    (void*)&cw0, (void*)&cw1, (void*)&cw2, (void*)&cw3, (void*)&cb,
                    (void*)&fc1W, (void*)&fc1b, (void*)&fc2W, (void*)&fc2b,
                    (void*)&ws, (void*)&out};
  hipError_t err = hipLaunchCooperativeKernel((const void*)k_mega,
                                              dim3(512), dim3(256), args, 0, stream);
  if (err != hipSuccess){
    (void)hipGetLastError();   // clear error state; fall back to multi-kernel path
    k_gpart    <<<dim3(64),  dim3(256), 0, stream>>>(x, ws);
    k_qkv      <<<dim3(32),  dim3(256), 0, stream>>>(x, cm1W, cm1b, cm2W, cm2b, ws);
    k_attn_main<<<dim3(512), dim3(256), 0, stream>>>(ws);
    k_attn_sum <<<dim3(544), dim3(256), 0, stream>>>(ws);
    k_attn_epi <<<dim3(32),  dim3(256), 0, stream>>>(cm1W, cm1b, cm2W, cm2b, ws);
    k_conv01   <<<dim3(240), dim3(256), 0, stream>>>(cw0, cw1, cb, ws);
    k_conv2    <<<dim3(30),  dim3(256), 0, stream>>>(cw2, cb, ws);
    k_tail     <<<dim3(1),   dim3(256), 0, stream>>>(cw3, cb, fc1W, fc1b, fc2W, fc2b, ws, out);
  }
}

// Round 14
// 61.851 us; speedup vs baseline: 6.9568x; 6.9568x over previous
//
#include <hip/hip_runtime.h>

#define TT 4096
#define KS 8

// ws float offsets (total 1,671,168 floats = 6.7 MB)
#define OFF_GPART 0        // [2][256][64] transposed partials
#define OFF_QH    32768    // bf16 [2][4096][16]
#define OFF_QL    98304
#define OFF_KH    163840
#define OFF_KL    229376
#define OFF_VT    294912   // bf16 [2][16][4096] (V transposed)
#define OFF_Y     360448   // [48][4096]
#define OFF_P     557056   // [2][KS][17][4096] flash partials (l, acc0..15), fixed-shift
#define OFF_C1    557056   // alias (conv stage runs after attn complete) (5,12,1023)
#define OFF_C2    618496   // (5,6,255)

typedef __attribute__((ext_vector_type(8))) short short8;
typedef __attribute__((ext_vector_type(4))) float f32x4;

__device__ __forceinline__ float relu6f(float v){ return fminf(fmaxf(v, 0.f), 6.f); }
__device__ __forceinline__ unsigned short f2bf(float f){   // RNE float->bf16 bits
  unsigned int u = __float_as_uint(f);
  return (unsigned short)((u + 0x7FFFu + ((u>>16)&1u)) >> 16);
}
__device__ __forceinline__ float bf2f(unsigned short s){
  return __uint_as_float(((unsigned int)s)<<16);
}

// ---------------- G partials (transposed): GPART[cm][ij][blk] ----------------
__global__ __launch_bounds__(256) void k_gpart(const float* __restrict__ x, float* __restrict__ ws){
  const int b = blockIdx.x, tid = threadIdx.x;        // 64 blocks x 64 t
  const int i = tid >> 4, j = tid & 15;
  const int t0 = b*64;
  const float4* ei4 = reinterpret_cast<const float4*>(x + (size_t)(1+i)*TT + t0);
  const float4* ej4 = reinterpret_cast<const float4*>(x + (size_t)(1+j)*TT + t0);
  const float4* wA4 = reinterpret_cast<const float4*>(x + t0);
  const float4* wB4 = reinterpret_cast<const float4*>(x + (size_t)17*TT + t0);
  float gA = 0.f, gB = 0.f;
  #pragma unroll 4
  for (int u = 0; u < 16; ++u){
    float4 a = ei4[u], c = ej4[u], wa = wA4[u], wb = wB4[u];
    float p0 = a.x*c.x, p1 = a.y*c.y, p2 = a.z*c.z, p3 = a.w*c.w;
    gA = fmaf(wa.x, p0, gA); gA = fmaf(wa.y, p1, gA); gA = fmaf(wa.z, p2, gA); gA = fmaf(wa.w, p3, gA);
    gB = fmaf(wb.x, p0, gB); gB = fmaf(wb.y, p1, gB); gB = fmaf(wb.z, p2, gB); gB = fmaf(wb.w, p3, gB);
  }
  ws[OFF_GPART + (size_t)tid*64 + b]         = gA;   // cm=0
  ws[OFF_GPART + (size_t)(256+tid)*64 + b]   = gB;   // cm=1
}

// ---------------- QKV -> bf16 (hi/lo split for Q,K; transposed bf16 V) ----------------
__global__ __launch_bounds__(128) void k_qkv(const float* __restrict__ x,
    const float* __restrict__ cm1W, const float* __restrict__ cm1b,
    const float* __restrict__ cm2W, const float* __restrict__ cm2b,
    float* __restrict__ ws){
  __shared__ float4 sG4[64];
  __shared__ float4 sW0[64], sW1[64], sW2[64];
  __shared__ float sB[48];
  const int b = blockIdx.x;           // 64 blocks: cm = b>>5
  const int cm = b >> 5;
  const int tid = threadIdx.x;        // 128 threads
  {
    const float4* g4a = reinterpret_cast<const float4*>(ws + OFF_GPART + (size_t)(cm*256 + tid)*64);
    const float4* g4b = reinterpret_cast<const float4*>(ws + OFF_GPART + (size_t)(cm*256 + 128 + tid)*64);
    float g0 = 0.f, g1 = 0.f;
    #pragma unroll
    for (int u = 0; u < 16; ++u){
      float4 a = g4a[u], c = g4b[u];
      g0 += (a.x + a.y) + (a.z + a.w);
      g1 += (c.x + c.y) + (c.z + c.w);
    }
    ((float*)sG4)[tid]       = g0;
    ((float*)sG4)[tid + 128] = g1;
  }
  const float* W  = cm ? cm2W : cm1W;
  const float* Bb = cm ? cm2b : cm1b;
  ((float*)sW0)[tid]       = W[tid];
  ((float*)sW0)[tid + 128] = W[tid + 128];
  ((float*)sW1)[tid]       = W[256 + tid];
  ((float*)sW1)[tid + 128] = W[384 + tid];
  ((float*)sW2)[tid]       = W[512 + tid];
  ((float*)sW2)[tid + 128] = W[640 + tid];
  if (tid < 48) sB[tid] = Bb[tid];
  __syncthreads();

  const int t = (b & 31)*128 + tid;
  float e[16], p[16], w2[16];
  const float wav = x[(size_t)(cm ? 17 : 0)*TT + t];
  #pragma unroll
  for (int d = 0; d < 16; ++d){ e[d] = x[(size_t)(1+d)*TT + t]; p[d] = wav * e[d]; }

  #pragma unroll
  for (int c = 0; c < 16; ++c){
    float a = 0.f;
    #pragma unroll
    for (int dv = 0; dv < 4; ++dv){
      float4 gv = sG4[c*4+dv];
      a = fmaf(gv.x, p[4*dv+0], a); a = fmaf(gv.y, p[4*dv+1], a);
      a = fmaf(gv.z, p[4*dv+2], a); a = fmaf(gv.w, p[4*dv+3], a);
    }
    w2[c] = a;
  }
  float q[16], kk[16], vv[16];
  #pragma unroll
  for (int c = 0; c < 16; ++c){
    float aq = sB[c], ak = sB[16+c], av = sB[32+c];
    #pragma unroll
    for (int dv = 0; dv < 4; ++dv){
      float4 w0 = sW0[c*4+dv], w1 = sW1[c*4+dv], w3 = sW2[c*4+dv];
      aq = fmaf(w0.x, e[4*dv+0], aq);  aq = fmaf(w0.y, e[4*dv+1], aq);
      aq = fmaf(w0.z, e[4*dv+2], aq);  aq = fmaf(w0.w, e[4*dv+3], aq);
      ak = fmaf(w1.x, w2[4*dv+0], ak); ak = fmaf(w1.y, w2[4*dv+1], ak);
      ak = fmaf(w1.z, w2[4*dv+2], ak); ak = fmaf(w1.w, w2[4*dv+3], ak);
      av = fmaf(w3.x, w2[4*dv+0], av); av = fmaf(w3.y, w2[4*dv+1], av);
      av = fmaf(w3.z, w2[4*dv+2], av); av = fmaf(w3.w, w2[4*dv+3], av);
    }
    q[c] = relu6f(aq); kk[c] = relu6f(ak); vv[c] = relu6f(av);
  }
  unsigned short qhv[16], qlv[16], khv[16], klv[16];
  #pragma unroll
  for (int d = 0; d < 16; ++d){
    qhv[d] = f2bf(q[d]);  qlv[d] = f2bf(q[d]  - bf2f(qhv[d]));
    khv[d] = f2bf(kk[d]); klv[d] = f2bf(kk[d] - bf2f(khv[d]));
  }
  const size_t rowus = ((size_t)cm*TT + t)*16;
  unsigned int wq[8];
  #pragma unroll
  for (int xx = 0; xx < 8; ++xx) wq[xx] = (unsigned int)qhv[2*xx] | ((unsigned int)qhv[2*xx+1]<<16);
  ((uint4*)((unsigned short*)(ws+OFF_QH)+rowus))[0] = make_uint4(wq[0],wq[1],wq[2],wq[3]);
  ((uint4*)((unsigned short*)(ws+OFF_QH)+rowus))[1] = make_uint4(wq[4],wq[5],wq[6],wq[7]);
  #pragma unroll
  for (int xx = 0; xx < 8; ++xx) wq[xx] = (unsigned int)qlv[2*xx] | ((unsigned int)qlv[2*xx+1]<<16);
  ((uint4*)((unsigned short*)(ws+OFF_QL)+rowus))[0] = make_uint4(wq[0],wq[1],wq[2],wq[3]);
  ((uint4*)((unsigned short*)(ws+OFF_QL)+rowus))[1] = make_uint4(wq[4],wq[5],wq[6],wq[7]);
  #pragma unroll
  for (int xx = 0; xx < 8; ++xx) wq[xx] = (unsigned int)khv[2*xx] | ((unsigned int)khv[2*xx+1]<<16);
  ((uint4*)((unsigned short*)(ws+OFF_KH)+rowus))[0] = make_uint4(wq[0],wq[1],wq[2],wq[3]);
  ((uint4*)((unsigned short*)(ws+OFF_KH)+rowus))[1] = make_uint4(wq[4],wq[5],wq[6],wq[7]);
  #pragma unroll
  for (int xx = 0; xx < 8; ++xx) wq[xx] = (unsigned int)klv[2*xx] | ((unsigned int)klv[2*xx+1]<<16);
  ((uint4*)((unsigned short*)(ws+OFF_KL)+rowus))[0] = make_uint4(wq[0],wq[1],wq[2],wq[3]);
  ((uint4*)((unsigned short*)(ws+OFF_KL)+rowus))[1] = make_uint4(wq[4],wq[5],wq[6],wq[7]);
  unsigned short* vtp = (unsigned short*)(ws+OFF_VT) + (size_t)cm*16*TT;
  #pragma unroll
  for (int d = 0; d < 16; ++d) vtp[(size_t)d*TT + t] = f2bf(vv[d]);

  if (cm == 0){
    #pragma unroll
    for (int d = 0; d < 16; ++d) ws[OFF_Y + (size_t)(16+d)*TT + t] = e[d];
  }
}

// ---------------- MFMA attention: full-K packed [Kh|Kl]x[Qh+Ql], 2 q-tiles/wave ----------------
__global__ __launch_bounds__(256) void k_attn_main(float* __restrict__ ws){
  const int unit = blockIdx.x*4 + (threadIdx.x >> 6);   // 2048 wave units
  const int lane = threadIdx.x & 63;
  const int cm = unit >> 10;
  const int rem = unit & 1023;
  const int qt2 = rem >> 3;         // 128 q-pair tiles (32 queries)
  const int ks = rem & 7;           // 8 key slices of 512
  const int i = lane & 15, g = lane >> 4;
  const int gb = (g & 1) * 8;       // col offset within the 16-d half

  const unsigned short* qh = (const unsigned short*)(ws + OFF_QH) + (size_t)cm*TT*16;
  const unsigned short* ql = (const unsigned short*)(ws + OFF_QL) + (size_t)cm*TT*16;
  const unsigned short* kh = (const unsigned short*)(ws + OFF_KH) + (size_t)cm*TT*16;
  const unsigned short* kl = (const unsigned short*)(ws + OFF_KL) + (size_t)cm*TT*16;
  const unsigned short* vt = (const unsigned short*)(ws + OFF_VT) + (size_t)cm*16*TT;
  const unsigned short* kbase = (g < 2) ? kh : kl;   // A rows: [Kh | Kl] along K-dim

  const int qA = qt2*32 + i, qB = qA + 16;
  const short8 b1A = *(const short8*)(qh + (size_t)qA*16 + gb);
  const short8 b2A = *(const short8*)(ql + (size_t)qA*16 + gb);
  const short8 b1B = *(const short8*)(qh + (size_t)qB*16 + gb);
  const short8 b2B = *(const short8*)(ql + (size_t)qB*16 + gb);

  const int key0 = ks*512;
  const int keyA = ((i>>2)<<3) + (i&3);    // interleave permute pi(i)
  f32x4 accA = {0.f,0.f,0.f,0.f}, accB = {0.f,0.f,0.f,0.f};
  float lsumA = 0.f, lsumB = 0.f;

  for (int t = 0; t < 16; ++t){
    const int k0 = key0 + t*32;
    const short8 a0 = *(const short8*)(kbase + ((size_t)(k0 + keyA))*16 + gb);
    const short8 a1 = *(const short8*)(kbase + ((size_t)(k0 + keyA + 4))*16 + gb);
    f32x4 d0A = {0.f,0.f,0.f,0.f}, d1A = {0.f,0.f,0.f,0.f};
    f32x4 d0B = {0.f,0.f,0.f,0.f}, d1B = {0.f,0.f,0.f,0.f};
    d0A = __builtin_amdgcn_mfma_f32_16x16x32_bf16(a0, b1A, d0A, 0,0,0);
    d0A = __builtin_amdgcn_mfma_f32_16x16x32_bf16(a0, b2A, d0A, 0,0,0);
    d1A = __builtin_amdgcn_mfma_f32_16x16x32_bf16(a1, b1A, d1A, 0,0,0);
    d1A = __builtin_amdgcn_mfma_f32_16x16x32_bf16(a1, b2A, d1A, 0,0,0);
    d0B = __builtin_amdgcn_mfma_f32_16x16x32_bf16(a0, b1B, d0B, 0,0,0);
    d0B = __builtin_amdgcn_mfma_f32_16x16x32_bf16(a0, b2B, d0B, 0,0,0);
    d1B = __builtin_amdgcn_mfma_f32_16x16x32_bf16(a1, b1B, d1B, 0,0,0);
    d1B = __builtin_amdgcn_mfma_f32_16x16x32_bf16(a1, b2B, d1B, 0,0,0);
    float p0A[4], p1A[4], p0B[4], p1B[4];
    #pragma unroll
    for (int r = 0; r < 4; ++r){
      p0A[r] = __expf(fminf(d0A[r],100.f) - 32.f); lsumA += p0A[r];
      p1A[r] = __expf(fminf(d1A[r],100.f) - 32.f); lsumA += p1A[r];
      p0B[r] = __expf(fminf(d0B[r],100.f) - 32.f); lsumB += p0B[r];
      p1B[r] = __expf(fminf(d1B[r],100.f) - 32.f); lsumB += p1B[r];
    }
    short8 paA, paB;
    #pragma unroll
    for (int r = 0; r < 4; ++r){
      paA[r]   = (short)f2bf(p0A[r]);
      paA[r+4] = (short)f2bf(p1A[r]);
      paB[r]   = (short)f2bf(p0B[r]);
      paB[r+4] = (short)f2bf(p1B[r]);
    }
    const short8 bv = *(const short8*)(vt + (size_t)i*TT + k0 + g*8);
    accA = __builtin_amdgcn_mfma_f32_16x16x32_bf16(paA, bv, accA, 0,0,0);
    accB = __builtin_amdgcn_mfma_f32_16x16x32_bf16(paB, bv, accB, 0,0,0);
  }
  lsumA += __shfl_xor(lsumA, 16);  lsumA += __shfl_xor(lsumA, 32);
  lsumB += __shfl_xor(lsumB, 16);  lsumB += __shfl_xor(lsumB, 32);
  float* Pb = ws + OFF_P + (size_t)((cm*KS + ks)*17)*TT;
  if (lane < 16){
    Pb[qt2*32 + lane]      = lsumA;
    Pb[qt2*32 + 16 + lane] = lsumB;
  }
  #pragma unroll
  for (int r = 0; r < 4; ++r){
    Pb[(size_t)(1 + i)*TT + qt2*32 + g*4 + r]      = accA[r];
    Pb[(size_t)(1 + i)*TT + qt2*32 + 16 + g*4 + r] = accB[r];
  }
}

// ---------------- fused sum-over-ks + /l + softmax16 + W3 -> y rows ----------------
// 8 independent loads per plane (MLP=8), 17 planes; coalesced across q.
__device__ __forceinline__ float sum8(const float* __restrict__ p){
  const size_t PL = (size_t)17*TT;
  float s0 = p[0],      s1 = p[PL],   s2 = p[2*PL], s3 = p[3*PL];
  float s4 = p[4*PL],   s5 = p[5*PL], s6 = p[6*PL], s7 = p[7*PL];
  return ((s0+s1)+(s2+s3)) + ((s4+s5)+(s6+s7));
}

__global__ __launch_bounds__(256) void k_attn_fin(
    const float* __restrict__ cm1W, const float* __restrict__ cm1b,
    const float* __restrict__ cm2W, const float* __restrict__ cm2b,
    float* __restrict__ ws){
  const int gid = blockIdx.x*256 + threadIdx.x;   // 32 blocks x 256
  const int cm = gid >> 12;
  const int q = gid & 4095;
  const float* Pb = ws + OFF_P + (size_t)cm*KS*17*TT + q;
  const float lt = sum8(Pb);
  float a[16];
  #pragma unroll
  for (int d = 0; d < 16; ++d) a[d] = sum8(Pb + (size_t)(1+d)*TT);
  const float invl = 1.f/lt;
  float mx = -1e30f;
  #pragma unroll
  for (int d = 0; d < 16; ++d){ a[d] *= invl; mx = fmaxf(mx, a[d]); }
  float es = 0.f;
  #pragma unroll
  for (int d = 0; d < 16; ++d){ a[d] = __expf(a[d]-mx); es += a[d]; }
  const float invs = 1.f/es;
  const float* W  = cm ? cm2W : cm1W;
  const float* Bb = cm ? cm2b : cm1b;
  #pragma unroll
  for (int c = 0; c < 16; ++c){
    float o = 0.f;
    #pragma unroll
    for (int d = 0; d < 16; ++d) o = fmaf(W[768 + c*16 + d], a[d], o);
    o = relu6f(fmaf(o, invs, Bb[48 + c]));
    ws[OFF_Y + (size_t)((cm ? 32 : 0) + c)*TT + q] = o;
  }
}

// ---------------- fused conv0+conv1: Y(48,4096) -> C1(5,12,1023) ----------------
__global__ __launch_bounds__(256) void k_conv01(const float* __restrict__ cw0,
    const float* __restrict__ cw1, const float* __restrict__ cb, float* __restrict__ ws){
  const int idx = blockIdx.x*256 + threadIdx.x;   // 240 blocks
  const int WO = 1023, HO = 12;
  if (idx >= 5*HO*WO) return;
  const int ow = idx % WO; int tmp = idx / WO;
  const int oh = tmp % HO; const int oc = tmp / HO;
  const float* y = ws + OFF_Y;
  float yp[4][7];
  #pragma unroll
  for (int r = 0; r < 4; ++r){
    const float* yr = y + (size_t)(4*oh + r)*TT + 4*ow;
    #pragma unroll
    for (int cx = 0; cx < 7; ++cx) yp[r][cx] = yr[cx];
  }
  float a = cb[5 + oc];
  #pragma unroll
  for (int ic = 0; ic < 5; ++ic){
    const float* w0 = cw0 + ic*6;
    const float* w1 = cw1 + ((oc*5+ic)*2)*4;
    #pragma unroll
    for (int kh = 0; kh < 2; ++kh){
      #pragma unroll
      for (int kw = 0; kw < 4; ++kw){
        float c0 = cb[ic];
        c0 = fmaf(w0[0], yp[2*kh][kw],   c0);
        c0 = fmaf(w0[1], yp[2*kh][kw+1], c0);
        c0 = fmaf(w0[2], yp[2*kh][kw+2], c0);
        c0 = fmaf(w0[3], yp[2*kh+1][kw],   c0);
        c0 = fmaf(w0[4], yp[2*kh+1][kw+1], c0);
        c0 = fmaf(w0[5], yp[2*kh+1][kw+2], c0);
        c0 = relu6f(c0);
        a = fmaf(w1[kh*4+kw], c0, a);
      }
    }
  }
  ws[OFF_C1 + idx] = relu6f(a);
}

// ---------------- conv2: (5,12,1023) -> (5,6,255) ----------------
__global__ __launch_bounds__(256) void k_conv2(const float* __restrict__ cw2,
    const float* __restrict__ cb, float* __restrict__ ws){
  const int idx = blockIdx.x*256 + threadIdx.x;
  if (idx >= 5*6*255) return;
  const int ow = idx % 255; int tmp = idx/255;
  const int oh = tmp % 6; const int oc = tmp/6;
  const float* c1 = ws + OFF_C1;
  float a = cb[10 + oc];
  #pragma unroll
  for (int ic = 0; ic < 5; ++ic)
    #pragma unroll
    for (int kh = 0; kh < 2; ++kh)
      #pragma unroll
      for (int kw = 0; kw < 4; ++kw)
        a = fmaf(cw2[((oc*5+ic)*2+kh)*4+kw], c1[(size_t)(ic*12 + 2*oh+kh)*1023 + 4*ow+kw], a);
  ws[OFF_C2 + idx] = relu6f(a);
}

// ---------------- tail: conv3 -> fc1(sigmoid) -> fc2(softmax) ----------------
__global__ __launch_bounds__(256) void k_tail(
    const float* __restrict__ cw3, const float* __restrict__ cb,
    const float* __restrict__ fc1W, const float* __restrict__ fc1b,
    const float* __restrict__ fc2W, const float* __restrict__ fc2b,
    const float* __restrict__ ws, float* __restrict__ out){
  __shared__ float c2[5*6*255];
  __shared__ float c3[5*3*84];
  __shared__ float hsm[42*15];
  const int tid = threadIdx.x;
  {
    const float4* src4 = reinterpret_cast<const float4*>(ws + OFF_C2);
    float4* c24 = reinterpret_cast<float4*>(c2);
    for (int i = tid; i < 1912; i += 256) c24[i] = src4[i];
    if (tid < 2) c2[7648 + tid] = ws[OFF_C2 + 7648 + tid];
  }
  __syncthreads();
  for (int idx = tid; idx < 5*3*84; idx += 256){
    const int ow = idx % 84; int tmp = idx/84;
    const int oh = tmp % 3; const int oc = tmp/3;
    float a = cb[15 + oc];
    #pragma unroll
    for (int ic = 0; ic < 5; ++ic)
      #pragma unroll
      for (int kh = 0; kh < 2; ++kh)
        #pragma unroll
        for (int kw = 0; kw < 4; ++kw)
          a = fmaf(cw3[((oc*5+ic)*2+kh)*4+kw], c2[(ic*6 + 2*oh+kh)*255 + 3*ow+kw], a);
    c3[idx] = relu6f(a);
  }
  __syncthreads();
  for (int i = tid; i < 630; i += 256){
    const int s = i / 15, kx = i % 15;
    const float* row = c3 + s*30;
    float a = fc1b[kx];
    #pragma unroll
    for (int n = 0; n < 30; ++n) a = fmaf(fc1W[kx*30+n], row[n], a);
    hsm[i] = 1.f/(1.f + __expf(-a));
  }
  __syncthreads();
  if (tid < 42){
    const float* h = hsm + tid*15;
    float l0 = fc2b[0], l1 = fc2b[1];
    #pragma unroll
    for (int kx = 0; kx < 15; ++kx){
      l0 = fmaf(fc2W[kx],    h[kx], l0);
      l1 = fmaf(fc2W[15+kx], h[kx], l1);
    }
    float mx = fmaxf(l0, l1);
    float e0 = __expf(l0-mx), e1 = __expf(l1-mx);
    float s = e0 + e1;
    out[tid*2]   = e0/s;
    out[tid*2+1] = e1/s;
  }
}

extern "C" void kernel_launch(void* const* d_in, const int* in_sizes, int n_in,
                              void* d_out, int out_size, void* d_ws, size_t ws_size,
                              hipStream_t stream){
  const float* x    = (const float*)d_in[0];
  const float* cm1W = (const float*)d_in[1];
  const float* cm1b = (const float*)d_in[2];
  const float* cm2W = (const float*)d_in[3];
  const float* cm2b = (const float*)d_in[4];
  const float* cw0  = (const float*)d_in[5];
  const float* cw1  = (const float*)d_in[6];
  const float* cw2  = (const float*)d_in[7];
  const float* cw3  = (const float*)d_in[8];
  const float* cb   = (const float*)d_in[9];
  const float* fc1W = (const float*)d_in[10];
  const float* fc1b = (const float*)d_in[11];
  const float* fc2W = (const float*)d_in[12];
  const float* fc2b = (const float*)d_in[13];
  float* ws  = (float*)d_ws;
  float* out = (float*)d_out;

  k_gpart    <<<dim3(64),  dim3(256), 0, stream>>>(x, ws);
  k_qkv      <<<dim3(64),  dim3(128), 0, stream>>>(x, cm1W, cm1b, cm2W, cm2b, ws);
  k_attn_main<<<dim3(512), dim3(256), 0, stream>>>(ws);
  k_attn_fin <<<dim3(32),  dim3(256), 0, stream>>>(cm1W, cm1b, cm2W, cm2b, ws);
  k_conv01   <<<dim3(240), dim3(256), 0, stream>>>(cw0, cw1, cb, ws);
  k_conv2    <<<dim3(30),  dim3(256), 0, stream>>>(cw2, cb, ws);
  k_tail     <<<dim3(1),   dim3(256), 0, stream>>>(cw3, cb, fc1W, fc1b, fc2W, fc2b, ws, out);
}

// Round 15
// 54.077 us; speedup vs baseline: 7.9568x; 1.1437x over previous
//
#include <hip/hip_runtime.h>

#define TT 4096
#define KS 8

// ws float offsets (total 1,671,168 floats = 6.7 MB)
#define OFF_GPART 0        // [2][256][64] transposed partials
#define OFF_QH    32768    // bf16 [2][4096][16]
#define OFF_QL    98304
#define OFF_KH    163840
#define OFF_KL    229376
#define OFF_VT    294912   // bf16 [2][16][4096] (V transposed)
#define OFF_Y     360448   // [48][4096]
#define OFF_P     557056   // [2][KS][17][4096] flash partials (l, acc0..15), fixed-shift
#define OFF_C1    557056   // alias (conv stage runs after attn complete) (5,12,1023)
#define OFF_C2    618496   // (5,6,255)

typedef __attribute__((ext_vector_type(8))) short short8;
typedef __attribute__((ext_vector_type(4))) float f32x4;

__device__ __forceinline__ float relu6f(float v){ return fminf(fmaxf(v, 0.f), 6.f); }
__device__ __forceinline__ unsigned short f2bf(float f){   // RNE float->bf16 bits
  unsigned int u = __float_as_uint(f);
  return (unsigned short)((u + 0x7FFFu + ((u>>16)&1u)) >> 16);
}
__device__ __forceinline__ float bf2f(unsigned short s){
  return __uint_as_float(((unsigned int)s)<<16);
}

// ---------------- G partials (transposed): GPART[cm][ij][blk] ----------------
__global__ __launch_bounds__(256) void k_gpart(const float* __restrict__ x, float* __restrict__ ws){
  const int b = blockIdx.x, tid = threadIdx.x;        // 64 blocks x 64 t
  const int i = tid >> 4, j = tid & 15;
  const int t0 = b*64;
  const float4* ei4 = reinterpret_cast<const float4*>(x + (size_t)(1+i)*TT + t0);
  const float4* ej4 = reinterpret_cast<const float4*>(x + (size_t)(1+j)*TT + t0);
  const float4* wA4 = reinterpret_cast<const float4*>(x + t0);
  const float4* wB4 = reinterpret_cast<const float4*>(x + (size_t)17*TT + t0);
  float gA = 0.f, gB = 0.f;
  #pragma unroll 4
  for (int u = 0; u < 16; ++u){
    float4 a = ei4[u], c = ej4[u], wa = wA4[u], wb = wB4[u];
    float p0 = a.x*c.x, p1 = a.y*c.y, p2 = a.z*c.z, p3 = a.w*c.w;
    gA = fmaf(wa.x, p0, gA); gA = fmaf(wa.y, p1, gA); gA = fmaf(wa.z, p2, gA); gA = fmaf(wa.w, p3, gA);
    gB = fmaf(wb.x, p0, gB); gB = fmaf(wb.y, p1, gB); gB = fmaf(wb.z, p2, gB); gB = fmaf(wb.w, p3, gB);
  }
  ws[OFF_GPART + (size_t)tid*64 + b]         = gA;   // cm=0
  ws[OFF_GPART + (size_t)(256+tid)*64 + b]   = gB;   // cm=1
}

// ---------------- QKV -> bf16 (hi/lo split for Q,K; transposed bf16 V) ----------------
__global__ __launch_bounds__(128) void k_qkv(const float* __restrict__ x,
    const float* __restrict__ cm1W, const float* __restrict__ cm1b,
    const float* __restrict__ cm2W, const float* __restrict__ cm2b,
    float* __restrict__ ws){
  __shared__ float4 sG4[64];
  __shared__ float4 sW0[64], sW1[64], sW2[64];
  __shared__ float sB[48];
  const int b = blockIdx.x;           // 64 blocks: cm = b>>5
  const int cm = b >> 5;
  const int tid = threadIdx.x;        // 128 threads
  {
    const float4* g4a = reinterpret_cast<const float4*>(ws + OFF_GPART + (size_t)(cm*256 + tid)*64);
    const float4* g4b = reinterpret_cast<const float4*>(ws + OFF_GPART + (size_t)(cm*256 + 128 + tid)*64);
    float g0 = 0.f, g1 = 0.f;
    #pragma unroll
    for (int u = 0; u < 16; ++u){
      float4 a = g4a[u], c = g4b[u];
      g0 += (a.x + a.y) + (a.z + a.w);
      g1 += (c.x + c.y) + (c.z + c.w);
    }
    ((float*)sG4)[tid]       = g0;
    ((float*)sG4)[tid + 128] = g1;
  }
  const float* W  = cm ? cm2W : cm1W;
  const float* Bb = cm ? cm2b : cm1b;
  ((float*)sW0)[tid]       = W[tid];
  ((float*)sW0)[tid + 128] = W[tid + 128];
  ((float*)sW1)[tid]       = W[256 + tid];
  ((float*)sW1)[tid + 128] = W[384 + tid];
  ((float*)sW2)[tid]       = W[512 + tid];
  ((float*)sW2)[tid + 128] = W[640 + tid];
  if (tid < 48) sB[tid] = Bb[tid];
  __syncthreads();

  const int t = (b & 31)*128 + tid;
  float e[16], p[16], w2[16];
  const float wav = x[(size_t)(cm ? 17 : 0)*TT + t];
  #pragma unroll
  for (int d = 0; d < 16; ++d){ e[d] = x[(size_t)(1+d)*TT + t]; p[d] = wav * e[d]; }

  #pragma unroll
  for (int c = 0; c < 16; ++c){
    float a = 0.f;
    #pragma unroll
    for (int dv = 0; dv < 4; ++dv){
      float4 gv = sG4[c*4+dv];
      a = fmaf(gv.x, p[4*dv+0], a); a = fmaf(gv.y, p[4*dv+1], a);
      a = fmaf(gv.z, p[4*dv+2], a); a = fmaf(gv.w, p[4*dv+3], a);
    }
    w2[c] = a;
  }
  float q[16], kk[16], vv[16];
  #pragma unroll
  for (int c = 0; c < 16; ++c){
    float aq = sB[c], ak = sB[16+c], av = sB[32+c];
    #pragma unroll
    for (int dv = 0; dv < 4; ++dv){
      float4 w0 = sW0[c*4+dv], w1 = sW1[c*4+dv], w3 = sW2[c*4+dv];
      aq = fmaf(w0.x, e[4*dv+0], aq);  aq = fmaf(w0.y, e[4*dv+1], aq);
      aq = fmaf(w0.z, e[4*dv+2], aq);  aq = fmaf(w0.w, e[4*dv+3], aq);
      ak = fmaf(w1.x, w2[4*dv+0], ak); ak = fmaf(w1.y, w2[4*dv+1], ak);
      ak = fmaf(w1.z, w2[4*dv+2], ak); ak = fmaf(w1.w, w2[4*dv+3], ak);
      av = fmaf(w3.x, w2[4*dv+0], av); av = fmaf(w3.y, w2[4*dv+1], av);
      av = fmaf(w3.z, w2[4*dv+2], av); av = fmaf(w3.w, w2[4*dv+3], av);
    }
    q[c] = relu6f(aq); kk[c] = relu6f(ak); vv[c] = relu6f(av);
  }
  unsigned short qhv[16], qlv[16], khv[16], klv[16];
  #pragma unroll
  for (int d = 0; d < 16; ++d){
    qhv[d] = f2bf(q[d]);  qlv[d] = f2bf(q[d]  - bf2f(qhv[d]));
    khv[d] = f2bf(kk[d]); klv[d] = f2bf(kk[d] - bf2f(khv[d]));
  }
  const size_t rowus = ((size_t)cm*TT + t)*16;
  unsigned int wq[8];
  #pragma unroll
  for (int xx = 0; xx < 8; ++xx) wq[xx] = (unsigned int)qhv[2*xx] | ((unsigned int)qhv[2*xx+1]<<16);
  ((uint4*)((unsigned short*)(ws+OFF_QH)+rowus))[0] = make_uint4(wq[0],wq[1],wq[2],wq[3]);
  ((uint4*)((unsigned short*)(ws+OFF_QH)+rowus))[1] = make_uint4(wq[4],wq[5],wq[6],wq[7]);
  #pragma unroll
  for (int xx = 0; xx < 8; ++xx) wq[xx] = (unsigned int)qlv[2*xx] | ((unsigned int)qlv[2*xx+1]<<16);
  ((uint4*)((unsigned short*)(ws+OFF_QL)+rowus))[0] = make_uint4(wq[0],wq[1],wq[2],wq[3]);
  ((uint4*)((unsigned short*)(ws+OFF_QL)+rowus))[1] = make_uint4(wq[4],wq[5],wq[6],wq[7]);
  #pragma unroll
  for (int xx = 0; xx < 8; ++xx) wq[xx] = (unsigned int)khv[2*xx] | ((unsigned int)khv[2*xx+1]<<16);
  ((uint4*)((unsigned short*)(ws+OFF_KH)+rowus))[0] = make_uint4(wq[0],wq[1],wq[2],wq[3]);
  ((uint4*)((unsigned short*)(ws+OFF_KH)+rowus))[1] = make_uint4(wq[4],wq[5],wq[6],wq[7]);
  #pragma unroll
  for (int xx = 0; xx < 8; ++xx) wq[xx] = (unsigned int)klv[2*xx] | ((unsigned int)klv[2*xx+1]<<16);
  ((uint4*)((unsigned short*)(ws+OFF_KL)+rowus))[0] = make_uint4(wq[0],wq[1],wq[2],wq[3]);
  ((uint4*)((unsigned short*)(ws+OFF_KL)+rowus))[1] = make_uint4(wq[4],wq[5],wq[6],wq[7]);
  unsigned short* vtp = (unsigned short*)(ws+OFF_VT) + (size_t)cm*16*TT;
  #pragma unroll
  for (int d = 0; d < 16; ++d) vtp[(size_t)d*TT + t] = f2bf(vv[d]);

  if (cm == 0){
    #pragma unroll
    for (int d = 0; d < 16; ++d) ws[OFF_Y + (size_t)(16+d)*TT + t] = e[d];
  }
}

// ---------------- MFMA attention: full-K packed [Kh|Kl]x[Qh+Ql], 2 q-tiles/wave ----------------
__global__ __launch_bounds__(256) void k_attn_main(float* __restrict__ ws){
  const int unit = blockIdx.x*4 + (threadIdx.x >> 6);   // 2048 wave units
  const int lane = threadIdx.x & 63;
  const int cm = unit >> 10;
  const int rem = unit & 1023;
  const int qt2 = rem >> 3;         // 128 q-pair tiles (32 queries)
  const int ks = rem & 7;           // 8 key slices of 512
  const int i = lane & 15, g = lane >> 4;
  const int gb = (g & 1) * 8;       // col offset within the 16-d half

  const unsigned short* qh = (const unsigned short*)(ws + OFF_QH) + (size_t)cm*TT*16;
  const unsigned short* ql = (const unsigned short*)(ws + OFF_QL) + (size_t)cm*TT*16;
  const unsigned short* kh = (const unsigned short*)(ws + OFF_KH) + (size_t)cm*TT*16;
  const unsigned short* kl = (const unsigned short*)(ws + OFF_KL) + (size_t)cm*TT*16;
  const unsigned short* vt = (const unsigned short*)(ws + OFF_VT) + (size_t)cm*16*TT;
  const unsigned short* kbase = (g < 2) ? kh : kl;   // A rows: [Kh | Kl] along K-dim

  const int qA = qt2*32 + i, qB = qA + 16;
  const short8 b1A = *(const short8*)(qh + (size_t)qA*16 + gb);
  const short8 b2A = *(const short8*)(ql + (size_t)qA*16 + gb);
  const short8 b1B = *(const short8*)(qh + (size_t)qB*16 + gb);
  const short8 b2B = *(const short8*)(ql + (size_t)qB*16 + gb);

  const int key0 = ks*512;
  const int keyA = ((i>>2)<<3) + (i&3);    // interleave permute pi(i)
  f32x4 accA = {0.f,0.f,0.f,0.f}, accB = {0.f,0.f,0.f,0.f};
  float lsumA = 0.f, lsumB = 0.f;

  for (int t = 0; t < 16; ++t){
    const int k0 = key0 + t*32;
    const short8 a0 = *(const short8*)(kbase + ((size_t)(k0 + keyA))*16 + gb);
    const short8 a1 = *(const short8*)(kbase + ((size_t)(k0 + keyA + 4))*16 + gb);
    f32x4 d0A = {0.f,0.f,0.f,0.f}, d1A = {0.f,0.f,0.f,0.f};
    f32x4 d0B = {0.f,0.f,0.f,0.f}, d1B = {0.f,0.f,0.f,0.f};
    d0A = __builtin_amdgcn_mfma_f32_16x16x32_bf16(a0, b1A, d0A, 0,0,0);
    d0A = __builtin_amdgcn_mfma_f32_16x16x32_bf16(a0, b2A, d0A, 0,0,0);
    d1A = __builtin_amdgcn_mfma_f32_16x16x32_bf16(a1, b1A, d1A, 0,0,0);
    d1A = __builtin_amdgcn_mfma_f32_16x16x32_bf16(a1, b2A, d1A, 0,0,0);
    d0B = __builtin_amdgcn_mfma_f32_16x16x32_bf16(a0, b1B, d0B, 0,0,0);
    d0B = __builtin_amdgcn_mfma_f32_16x16x32_bf16(a0, b2B, d0B, 0,0,0);
    d1B = __builtin_amdgcn_mfma_f32_16x16x32_bf16(a1, b1B, d1B, 0,0,0);
    d1B = __builtin_amdgcn_mfma_f32_16x16x32_bf16(a1, b2B, d1B, 0,0,0);
    float p0A[4], p1A[4], p0B[4], p1B[4];
    #pragma unroll
    for (int r = 0; r < 4; ++r){
      p0A[r] = __expf(fminf(d0A[r],100.f) - 32.f); lsumA += p0A[r];
      p1A[r] = __expf(fminf(d1A[r],100.f) - 32.f); lsumA += p1A[r];
      p0B[r] = __expf(fminf(d0B[r],100.f) - 32.f); lsumB += p0B[r];
      p1B[r] = __expf(fminf(d1B[r],100.f) - 32.f); lsumB += p1B[r];
    }
    short8 paA, paB;
    #pragma unroll
    for (int r = 0; r < 4; ++r){
      paA[r]   = (short)f2bf(p0A[r]);
      paA[r+4] = (short)f2bf(p1A[r]);
      paB[r]   = (short)f2bf(p0B[r]);
      paB[r+4] = (short)f2bf(p1B[r]);
    }
    const short8 bv = *(const short8*)(vt + (size_t)i*TT + k0 + g*8);
    accA = __builtin_amdgcn_mfma_f32_16x16x32_bf16(paA, bv, accA, 0,0,0);
    accB = __builtin_amdgcn_mfma_f32_16x16x32_bf16(paB, bv, accB, 0,0,0);
  }
  lsumA += __shfl_xor(lsumA, 16);  lsumA += __shfl_xor(lsumA, 32);
  lsumB += __shfl_xor(lsumB, 16);  lsumB += __shfl_xor(lsumB, 32);
  float* Pb = ws + OFF_P + (size_t)((cm*KS + ks)*17)*TT;
  if (lane < 16){
    Pb[qt2*32 + lane]      = lsumA;
    Pb[qt2*32 + 16 + lane] = lsumB;
  }
  #pragma unroll
  for (int r = 0; r < 4; ++r){
    Pb[(size_t)(1 + i)*TT + qt2*32 + g*4 + r]      = accA[r];
    Pb[(size_t)(1 + i)*TT + qt2*32 + 16 + g*4 + r] = accB[r];
  }
}

// ---------------- wide fused sum-over-ks + /l + softmax16 + W3 -> y rows ----------------
// 512 blocks: block = (cm, 16-query group). Phase 1: thread (p,qo) sums plane over ks.
// Phase 2: thread (c,qo) does softmax + W3 channel c.
__global__ __launch_bounds__(256) void k_attn_fin2(
    const float* __restrict__ cm1W, const float* __restrict__ cm1b,
    const float* __restrict__ cm2W, const float* __restrict__ cm2b,
    float* __restrict__ ws){
  __shared__ float sA[16][16];   // acc plane sums [d][qo]
  __shared__ float sL[16];       // l sums [qo]
  const int b = blockIdx.x;      // 512: cm = b>>8, qb = b&255
  const int cm = b >> 8;
  const int qb = b & 255;
  const int tid = threadIdx.x;
  const int p = tid >> 4, qo = tid & 15;
  const int q = qb*16 + qo;
  const float* Pc = ws + OFF_P + (size_t)cm*KS*17*TT;
  const size_t PL = (size_t)17*TT;
  {
    const float* src = Pc + (size_t)(1+p)*TT + q;
    float s0 = src[0],    s1 = src[PL],   s2 = src[2*PL], s3 = src[3*PL];
    float s4 = src[4*PL], s5 = src[5*PL], s6 = src[6*PL], s7 = src[7*PL];
    sA[p][qo] = ((s0+s1)+(s2+s3)) + ((s4+s5)+(s6+s7));
    if (p == 0){
      const float* sl = Pc + q;
      float t0 = sl[0],    t1 = sl[PL],   t2 = sl[2*PL], t3 = sl[3*PL];
      float t4 = sl[4*PL], t5 = sl[5*PL], t6 = sl[6*PL], t7 = sl[7*PL];
      sL[qo] = ((t0+t1)+(t2+t3)) + ((t4+t5)+(t6+t7));
    }
  }
  __syncthreads();
  const int c = p;               // reuse thread layout: (c, qo)
  const float invl = 1.f / sL[qo];
  float a[16];
  float mx = -1e30f;
  #pragma unroll
  for (int d = 0; d < 16; ++d){ a[d] = sA[d][qo] * invl; mx = fmaxf(mx, a[d]); }
  float es = 0.f;
  #pragma unroll
  for (int d = 0; d < 16; ++d){ a[d] = __expf(a[d]-mx); es += a[d]; }
  const float invs = 1.f/es;
  const float* W  = cm ? cm2W : cm1W;
  const float* Bb = cm ? cm2b : cm1b;
  float o = 0.f;
  #pragma unroll
  for (int d = 0; d < 16; ++d) o = fmaf(W[768 + c*16 + d], a[d], o);
  o = relu6f(fmaf(o, invs, Bb[48 + c]));
  ws[OFF_Y + (size_t)((cm ? 32 : 0) + c)*TT + q] = o;
}

// ---------------- fused conv0+conv1: Y(48,4096) -> C1(5,12,1023) ----------------
__global__ __launch_bounds__(256) void k_conv01(const float* __restrict__ cw0,
    const float* __restrict__ cw1, const float* __restrict__ cb, float* __restrict__ ws){
  const int idx = blockIdx.x*256 + threadIdx.x;   // 240 blocks
  const int WO = 1023, HO = 12;
  if (idx >= 5*HO*WO) return;
  const int ow = idx % WO; int tmp = idx / WO;
  const int oh = tmp % HO; const int oc = tmp / HO;
  const float* y = ws + OFF_Y;
  float yp[4][7];
  #pragma unroll
  for (int r = 0; r < 4; ++r){
    const float* yr = y + (size_t)(4*oh + r)*TT + 4*ow;
    #pragma unroll
    for (int cx = 0; cx < 7; ++cx) yp[r][cx] = yr[cx];
  }
  float a = cb[5 + oc];
  #pragma unroll
  for (int ic = 0; ic < 5; ++ic){
    const float* w0 = cw0 + ic*6;
    const float* w1 = cw1 + ((oc*5+ic)*2)*4;
    #pragma unroll
    for (int kh = 0; kh < 2; ++kh){
      #pragma unroll
      for (int kw = 0; kw < 4; ++kw){
        float c0 = cb[ic];
        c0 = fmaf(w0[0], yp[2*kh][kw],   c0);
        c0 = fmaf(w0[1], yp[2*kh][kw+1], c0);
        c0 = fmaf(w0[2], yp[2*kh][kw+2], c0);
        c0 = fmaf(w0[3], yp[2*kh+1][kw],   c0);
        c0 = fmaf(w0[4], yp[2*kh+1][kw+1], c0);
        c0 = fmaf(w0[5], yp[2*kh+1][kw+2], c0);
        c0 = relu6f(c0);
        a = fmaf(w1[kh*4+kw], c0, a);
      }
    }
  }
  ws[OFF_C1 + idx] = relu6f(a);
}

// ---------------- conv2: (5,12,1023) -> (5,6,255) ----------------
__global__ __launch_bounds__(256) void k_conv2(const float* __restrict__ cw2,
    const float* __restrict__ cb, float* __restrict__ ws){
  const int idx = blockIdx.x*256 + threadIdx.x;
  if (idx >= 5*6*255) return;
  const int ow = idx % 255; int tmp = idx/255;
  const int oh = tmp % 6; const int oc = tmp/6;
  const float* c1 = ws + OFF_C1;
  float a = cb[10 + oc];
  #pragma unroll
  for (int ic = 0; ic < 5; ++ic)
    #pragma unroll
    for (int kh = 0; kh < 2; ++kh)
      #pragma unroll
      for (int kw = 0; kw < 4; ++kw)
        a = fmaf(cw2[((oc*5+ic)*2+kh)*4+kw], c1[(size_t)(ic*12 + 2*oh+kh)*1023 + 4*ow+kw], a);
  ws[OFF_C2 + idx] = relu6f(a);
}

// ---------------- tail: conv3 -> fc1(sigmoid) -> fc2(softmax) ----------------
__global__ __launch_bounds__(256) void k_tail(
    const float* __restrict__ cw3, const float* __restrict__ cb,
    const float* __restrict__ fc1W, const float* __restrict__ fc1b,
    const float* __restrict__ fc2W, const float* __restrict__ fc2b,
    const float* __restrict__ ws, float* __restrict__ out){
  __shared__ float c2[5*6*255];
  __shared__ float c3[5*3*84];
  __shared__ float hsm[42*15];
  const int tid = threadIdx.x;
  {
    const float4* src4 = reinterpret_cast<const float4*>(ws + OFF_C2);
    float4* c24 = reinterpret_cast<float4*>(c2);
    for (int i = tid; i < 1912; i += 256) c24[i] = src4[i];
    if (tid < 2) c2[7648 + tid] = ws[OFF_C2 + 7648 + tid];
  }
  __syncthreads();
  for (int idx = tid; idx < 5*3*84; idx += 256){
    const int ow = idx % 84; int tmp = idx/84;
    const int oh = tmp % 3; const int oc = tmp/3;
    float a = cb[15 + oc];
    #pragma unroll
    for (int ic = 0; ic < 5; ++ic)
      #pragma unroll
      for (int kh = 0; kh < 2; ++kh)
        #pragma unroll
        for (int kw = 0; kw < 4; ++kw)
          a = fmaf(cw3[((oc*5+ic)*2+kh)*4+kw], c2[(ic*6 + 2*oh+kh)*255 + 3*ow+kw], a);
    c3[idx] = relu6f(a);
  }
  __syncthreads();
  for (int i = tid; i < 630; i += 256){
    const int s = i / 15, kx = i % 15;
    const float* row = c3 + s*30;
    float a = fc1b[kx];
    #pragma unroll
    for (int n = 0; n < 30; ++n) a = fmaf(fc1W[kx*30+n], row[n], a);
    hsm[i] = 1.f/(1.f + __expf(-a));
  }
  __syncthreads();
  if (tid < 42){
    const float* h = hsm + tid*15;
    float l0 = fc2b[0], l1 = fc2b[1];
    #pragma unroll
    for (int kx = 0; kx < 15; ++kx){
      l0 = fmaf(fc2W[kx],    h[kx], l0);
      l1 = fmaf(fc2W[15+kx], h[kx], l1);
    }
    float mx = fmaxf(l0, l1);
    float e0 = __expf(l0-mx), e1 = __expf(l1-mx);
    float s = e0 + e1;
    out[tid*2]   = e0/s;
    out[tid*2+1] = e1/s;
  }
}

extern "C" void kernel_launch(void* const* d_in, const int* in_sizes, int n_in,
                              void* d_out, int out_size, void* d_ws, size_t ws_size,
                              hipStream_t stream){
  const float* x    = (const float*)d_in[0];
  const float* cm1W = (const float*)d_in[1];
  const float* cm1b = (const float*)d_in[2];
  const float* cm2W = (const float*)d_in[3];
  const float* cm2b = (const float*)d_in[4];
  const float* cw0  = (const float*)d_in[5];
  const float* cw1  = (const float*)d_in[6];
  const float* cw2  = (const float*)d_in[7];
  const float* cw3  = (const float*)d_in[8];
  const float* cb   = (const float*)d_in[9];
  const float* fc1W = (const float*)d_in[10];
  const float* fc1b = (const float*)d_in[11];
  const float* fc2W = (const float*)d_in[12];
  const float* fc2b = (const float*)d_in[13];
  float* ws  = (float*)d_ws;
  float* out = (float*)d_out;

  k_gpart    <<<dim3(64),  dim3(256), 0, stream>>>(x, ws);
  k_qkv      <<<dim3(64),  dim3(128), 0, stream>>>(x, cm1W, cm1b, cm2W, cm2b, ws);
  k_attn_main<<<dim3(512), dim3(256), 0, stream>>>(ws);
  k_attn_fin2<<<dim3(512), dim3(256), 0, stream>>>(cm1W, cm1b, cm2W, cm2b, ws);
  k_conv01   <<<dim3(240), dim3(256), 0, stream>>>(cw0, cw1, cb, ws);
  k_conv2    <<<dim3(30),  dim3(256), 0, stream>>>(cw2, cb, ws);
  k_tail     <<<dim3(1),   dim3(256), 0, stream>>>(cw3, cb, fc1W, fc1b, fc2W, fc2b, ws, out);
}